// Round 6
// baseline (158.247 us; speedup 1.0000x reference)
//
#include <hip/hip_runtime.h>
#include <stdint.h>

#define N 2048
#define TM 128            // block tile rows
#define TN 64             // block tile cols -> 512 blocks = 2 blocks/CU
#define BK 32
#define KI (N / BK)       // 64 K-iterations
#define LDSW 40           // padded LDS row stride in u16 (80 B)
#define ABUF 5120         // u16 per A staging buffer (128*LDSW)
#define BBUF 2560         // u16 per B staging buffer (64*LDSW)
#define BOFF (2 * ABUF)   // B area base (u16 index)
#define NN ((size_t)N * (size_t)N)

typedef unsigned short u16;
typedef __bf16 bf16x8 __attribute__((ext_vector_type(8)));
typedef unsigned short ushortx8 __attribute__((ext_vector_type(8)));
typedef float floatx4 __attribute__((ext_vector_type(4)));

static __device__ __forceinline__ u16 f2bf(float f) {
  unsigned int u = __builtin_bit_cast(unsigned int, f);
  return (u16)((u + 0x7fffu + ((u >> 16) & 1u)) >> 16);  // RNE, finite inputs
}

// ---------------------------------------------------------------------------
// cast + transpose: Ab[r][c] = bf16(A[r][c]); Abt[c][r] = bf16(A[r][c])
// ---------------------------------------------------------------------------
__global__ void cast_tr(const float* __restrict__ A, u16* __restrict__ Ab,
                        u16* __restrict__ Abt) {
  __shared__ float tile[32][33];
  const int tx = threadIdx.x, ty = threadIdx.y;
  const int c = blockIdx.x * 32 + tx;
#pragma unroll
  for (int i = 0; i < 4; i++) {
    const int r = blockIdx.y * 32 + ty + i * 8;
    const float v = A[r * N + c];
    Ab[r * N + c] = f2bf(v);
    tile[ty + i * 8][tx] = v;
  }
  __syncthreads();
  const int r2 = blockIdx.y * 32 + tx;
#pragma unroll
  for (int i = 0; i < 4; i++) {
    const int c2 = blockIdx.x * 32 + ty + i * 8;
    Abt[c2 * N + r2] = f2bf(tile[tx][ty + i * 8]);
  }
}

// ---------------------------------------------------------------------------
// Round-4 skeleton rescaled to 128x64 tiles (512 blocks = 2 blocks/CU).
// 256 threads = 4 waves in 2x2; wave tile 64x32 (4x2 MFMA 16x16x32).
// Register prefetch distance 3 (plain global_load_dwordx4 -> precise vmcnt),
// double-buffered LDS, 2 barriers/iter. Cross-block overlap at 2 blocks/CU
// hides the barrier drains (m114 mechanism).
// smem carve (u16): A: buf*ABUF (0..10239); B: BOFF + buf*BBUF (10240..15359)
// ---------------------------------------------------------------------------
__device__ __forceinline__ void gemm_core(u16* smem, const u16* __restrict__ L,
                                          const u16* __restrict__ Rt,
                                          floatx4 acc[4][2]) {
  const int t = threadIdx.x;  // 0..255
  const int row0 = blockIdx.y * TM;
  const int col0 = blockIdx.x * TN;

  // A staging: thread t covers row t>>1 (0..127), 32B chunk (t&1) (two x8)
  const int srA = t >> 1;
  const int scA = (t & 1) * 16;
  const u16* gA = L + (size_t)(row0 + srA) * N + scA;
  const int wbA = srA * LDSW + scA;
  // B staging: thread t covers row t>>2 (0..63), 16B chunk (t&3) (one x8)
  const int srB = t >> 2;
  const int scB = (t & 3) * 8;
  const u16* gB = Rt + (size_t)(col0 + srB) * N + scB;
  const int wbB = BOFF + srB * LDSW + scB;

  const int lane = t & 63;
  const int w = t >> 6;            // 0..3
  const int wr = (w >> 1) * 64;
  const int wc = (w & 1) * 32;
  const int lr = lane & 15;
  const int q = lane >> 4;
  const int raA = (wr + lr) * LDSW + q * 8;
  const int raB = BOFF + (wc + lr) * LDSW + q * 8;

#pragma unroll
  for (int i = 0; i < 4; i++)
#pragma unroll
    for (int j = 0; j < 2; j++) acc[i][j] = (floatx4){0.f, 0.f, 0.f, 0.f};

  ushortx8 rA[4][2], rB[4];
#pragma unroll
  for (int s = 0; s < 3; s++) {
    rA[s][0] = *(const ushortx8*)(gA + s * BK);
    rA[s][1] = *(const ushortx8*)(gA + s * BK + 8);
    rB[s] = *(const ushortx8*)(gB + s * BK);
  }
  *(ushortx8*)(&smem[wbA]) = rA[0][0];
  *(ushortx8*)(&smem[wbA + 8]) = rA[0][1];
  *(ushortx8*)(&smem[wbB]) = rB[0];
  __syncthreads();

#define GSTEP(i, s)                                                           \
  {                                                                           \
    if ((i) + 3 < KI) {                                                       \
      rA[((s) + 3) & 3][0] = *(const ushortx8*)(gA + ((i) + 3) * BK);         \
      rA[((s) + 3) & 3][1] = *(const ushortx8*)(gA + ((i) + 3) * BK + 8);     \
      rB[((s) + 3) & 3] = *(const ushortx8*)(gB + ((i) + 3) * BK);            \
    }                                                                         \
    bf16x8 af[4], bq[2];                                                      \
    _Pragma("unroll") for (int mt = 0; mt < 4; mt++) af[mt] =                 \
        __builtin_bit_cast(bf16x8, *(const ushortx8*)&smem[                   \
            raA + ((s) & 1) * ABUF + mt * 16 * LDSW]);                        \
    _Pragma("unroll") for (int nt = 0; nt < 2; nt++) bq[nt] =                 \
        __builtin_bit_cast(bf16x8, *(const ushortx8*)&smem[                   \
            raB + ((s) & 1) * BBUF + nt * 16 * LDSW]);                        \
    _Pragma("unroll") for (int mt = 0; mt < 4; mt++)                          \
        _Pragma("unroll") for (int nt = 0; nt < 2; nt++) acc[mt][nt] =        \
            __builtin_amdgcn_mfma_f32_16x16x32_bf16(af[mt], bq[nt],           \
                                                    acc[mt][nt], 0, 0, 0);    \
    __syncthreads(); /* all waves done reading buf[(s+1)&1] from iter i-1 */  \
    if ((i) + 1 < KI) {                                                       \
      *(ushortx8*)(&smem[wbA + (((s) + 1) & 1) * ABUF]) = rA[((s) + 1) & 3][0]; \
      *(ushortx8*)(&smem[wbA + (((s) + 1) & 1) * ABUF + 8]) =                 \
          rA[((s) + 1) & 3][1];                                               \
      *(ushortx8*)(&smem[wbB + (((s) + 1) & 1) * BBUF]) = rB[((s) + 1) & 3];  \
    }                                                                         \
    __syncthreads(); /* publish buf[(s+1)&1] for iter i+1 */                  \
  }

  for (int io = 0; io < KI; io += 4) {
    GSTEP(io + 0, 0)
    GSTEP(io + 1, 1)
    GSTEP(io + 2, 2)
    GSTEP(io + 3, 3)
  }
#undef GSTEP
}

// GEMM1: Mb = bf16(A@A); deg[row] += rowsum(M) (fused LDS + global atomics)
__global__ __launch_bounds__(256, 2) void gemm1(const u16* __restrict__ Ab,
                                                const u16* __restrict__ Abt,
                                                u16* __restrict__ Mb,
                                                float* __restrict__ deg) {
  __shared__ __align__(16) u16 smem[2 * ABUF + 2 * BBUF];
  floatx4 acc[4][2];
  gemm_core(smem, Ab, Abt, acc);

  float* rs = (float*)smem;  // K-loop fully barriered before reuse
  const int t = threadIdx.x;
  const int row0 = blockIdx.y * TM, col0 = blockIdx.x * TN;
  if (t < TM) rs[t] = 0.f;
  __syncthreads();
  const int lane = t & 63, w = t >> 6;
  const int wr = (w >> 1) * 64, wc = (w & 1) * 32;
  const int lr = lane & 15, q = lane >> 4;
  float trs[4][4];
#pragma unroll
  for (int mt = 0; mt < 4; mt++)
#pragma unroll
    for (int r = 0; r < 4; r++) trs[mt][r] = 0.f;
#pragma unroll
  for (int mt = 0; mt < 4; mt++)
#pragma unroll
    for (int nt = 0; nt < 2; nt++)
#pragma unroll
      for (int r = 0; r < 4; r++) {
        const float v = acc[mt][nt][r];
        const int rr = row0 + wr + mt * 16 + q * 4 + r;
        const int cc = col0 + wc + nt * 16 + lr;
        Mb[(size_t)rr * N + cc] = f2bf(v);
        trs[mt][r] += v;
      }
#pragma unroll
  for (int mt = 0; mt < 4; mt++)
#pragma unroll
    for (int r = 0; r < 4; r++)
      atomicAdd(&rs[wr + mt * 16 + q * 4 + r], trs[mt][r]);
  __syncthreads();
  if (t < TM) atomicAdd(&deg[row0 + t], rs[t]);
}

// GEMM2 + fused norm epilogue: out = (8*(M@A) + 2*A) / (4*deg+1) row-scaled
__global__ __launch_bounds__(256, 2) void gemm2(const u16* __restrict__ Mb,
                                                const u16* __restrict__ Abt,
                                                const float* __restrict__ A,
                                                const float* __restrict__ deg,
                                                float* __restrict__ out) {
  __shared__ __align__(16) u16 smem[2 * ABUF + 2 * BBUF];
  floatx4 acc[4][2];
  gemm_core(smem, Mb, Abt, acc);

  const int t = threadIdx.x;
  const int row0 = blockIdx.y * TM, col0 = blockIdx.x * TN;
  const int lane = t & 63, w = t >> 6;
  const int wr = (w >> 1) * 64, wc = (w & 1) * 32;
  const int lr = lane & 15, q = lane >> 4;
#pragma unroll
  for (int mt = 0; mt < 4; mt++)
#pragma unroll
    for (int r = 0; r < 4; r++) {
      const int rr = row0 + wr + mt * 16 + q * 4 + r;
      float d = 4.f * deg[rr] + 1.f;
      if (d <= 1e-10f) d = 1.f;
      const float rd = 1.f / d;
#pragma unroll
      for (int nt = 0; nt < 2; nt++) {
        const int cc = col0 + wc + nt * 16 + lr;
        out[(size_t)rr * N + cc] =
            (8.f * acc[mt][nt][r] + 2.f * A[(size_t)rr * N + cc]) * rd;
      }
    }
}

extern "C" void kernel_launch(void* const* d_in, const int* in_sizes, int n_in,
                              void* d_out, int out_size, void* d_ws, size_t ws_size,
                              hipStream_t stream) {
  const float* A = (const float*)d_in[0];
  // GTConv weights (d_in[1..3]) are irrelevant: softmax over a singleton axis
  // is identically 1, so each conv output is exactly 2*A.
  float* out = (float*)d_out;
  char* ws = (char*)d_ws;
  u16* Ab = (u16*)ws;                        // 8 MB bf16 A row-major
  u16* Abt = (u16*)(ws + NN * 2);            // 8 MB bf16 A transposed
  u16* Mb = (u16*)(ws + NN * 4);             // 8 MB bf16 M = A@A
  float* deg = (float*)(ws + NN * 6);        // 8 KB row sums of M

  hipMemsetAsync(deg, 0, N * sizeof(float), stream);
  cast_tr<<<dim3(N / 32, N / 32), dim3(32, 8), 0, stream>>>(A, Ab, Abt);
  gemm1<<<dim3(N / TN, N / TM), 256, 0, stream>>>(Ab, Abt, Mb, deg);
  gemm2<<<dim3(N / TN, N / TM), 256, 0, stream>>>(Mb, Abt, A, deg, out);
}

// Round 7
// 142.735 us; speedup vs baseline: 1.1087x; 1.1087x over previous
//
#include <hip/hip_runtime.h>
#include <stdint.h>

#define N 2048
#define TILE 128
#define BK 32
#define KI (N / BK)       // 64 K-iterations
#define LDSW 40           // padded LDS row stride in u16 (80 B)
#define ABUF (TILE * LDSW)  // 5120 u16 per staging buffer
#define BOFF (2 * ABUF)     // B area base (u16 index); total 4*ABUF = 40 KB
#define NN ((size_t)N * (size_t)N)

typedef unsigned short u16;
typedef __bf16 bf16x8 __attribute__((ext_vector_type(8)));
typedef unsigned short ushortx8 __attribute__((ext_vector_type(8)));
typedef unsigned short ushortx4 __attribute__((ext_vector_type(4)));
typedef float floatx4 __attribute__((ext_vector_type(4)));

static __device__ __forceinline__ u16 f2bf(float f) {
  unsigned int u = __builtin_bit_cast(unsigned int, f);
  return (u16)((u + 0x7fffu + ((u >> 16) & 1u)) >> 16);  // RNE, finite inputs
}

// ---------------------------------------------------------------------------
// cast + transpose, fully vectorized: float4 in, ushortx4 out on both paths.
// grid (64,64), block 256; 32x32 tile per block.
// ---------------------------------------------------------------------------
__global__ void cast_tr(const float* __restrict__ A, u16* __restrict__ Ab,
                        u16* __restrict__ Abt) {
  __shared__ float tile[32][33];
  const int u = threadIdx.x;      // 0..255
  const int r = u >> 3;           // 0..31
  const int c4 = (u & 7) * 4;     // 0..28
  const int gr = blockIdx.y * 32 + r;
  const int gc = blockIdx.x * 32 + c4;
  const float4 v = *(const float4*)(A + (size_t)gr * N + gc);
  ushortx4 o;
  o[0] = f2bf(v.x); o[1] = f2bf(v.y); o[2] = f2bf(v.z); o[3] = f2bf(v.w);
  *(ushortx4*)(Ab + (size_t)gr * N + gc) = o;
  tile[r][c4 + 0] = v.x; tile[r][c4 + 1] = v.y;
  tile[r][c4 + 2] = v.z; tile[r][c4 + 3] = v.w;
  __syncthreads();
  const int tc = u >> 3;          // col of A = row of Abt (0..31)
  const int rc = (u & 7) * 4;     // row-chunk of A (0..28)
  ushortx4 w;
#pragma unroll
  for (int j = 0; j < 4; j++) w[j] = f2bf(tile[rc + j][tc]);
  *(ushortx4*)(Abt + (size_t)(blockIdx.x * 32 + tc) * N + blockIdx.y * 32 + rc) = w;
}

// ---------------------------------------------------------------------------
// Round-4 skeleton, single barrier per K-iter.
// 512 threads = 8 waves (2/SIMD). Wave w: 64x32 subtile, wr=(w>>2)*64,
// wc=(w&3)*32, 4x2 MFMA 16x16x32. Register prefetch distance 3 via plain
// global_load_dwordx4 (precise per-wave vmcnt). Double-buffered LDS.
// Safety: iter i reads buf[i&1] (written iter i-1), writes buf[(i+1)&1]
// (last read in iter i-1) — both pairs separated by exactly one top barrier.
// smem carve (u16): A: buf*ABUF (0..10239); B: BOFF + buf*ABUF.
// ---------------------------------------------------------------------------
__device__ __forceinline__ void gemm_core(u16* smem, const u16* __restrict__ L,
                                          const u16* __restrict__ Rt,
                                          floatx4 acc[4][2]) {
  const int t = threadIdx.x;             // 0..511
  const int row0 = blockIdx.y * TILE;
  const int col0 = blockIdx.x * TILE;

  // staging: thread t covers row t>>2 (0..127), 16B chunk t&3 of each tile
  const int srow = t >> 2;
  const int sc = (t & 3) * 8;
  const u16* gA = L + (size_t)(row0 + srow) * N + sc;
  const u16* gB = Rt + (size_t)(col0 + srow) * N + sc;
  const int wb = srow * LDSW + sc;       // LDS write offset within a buffer

  const int lane = t & 63;
  const int w = t >> 6;                  // 0..7
  const int wr = (w >> 2) * 64;
  const int wc = (w & 3) * 32;
  const int lr = lane & 15;
  const int q = lane >> 4;
  const int raA = (wr + lr) * LDSW + q * 8;
  const int raB = BOFF + (wc + lr) * LDSW + q * 8;

#pragma unroll
  for (int i = 0; i < 4; i++)
#pragma unroll
    for (int j = 0; j < 2; j++) acc[i][j] = (floatx4){0.f, 0.f, 0.f, 0.f};

  ushortx8 rA[4], rB[4];
#pragma unroll
  for (int s = 0; s < 3; s++) {
    rA[s] = *(const ushortx8*)(gA + s * BK);
    rB[s] = *(const ushortx8*)(gB + s * BK);
  }
  // publish tile 0 into buf 0
  *(ushortx8*)(&smem[wb]) = rA[0];
  *(ushortx8*)(&smem[BOFF + wb]) = rB[0];

#define GSTEP(i, s)                                                           \
  {                                                                           \
    if ((i) + 3 < KI) {                                                       \
      rA[((s) + 3) & 3] = *(const ushortx8*)(gA + ((i) + 3) * BK);            \
      rB[((s) + 3) & 3] = *(const ushortx8*)(gB + ((i) + 3) * BK);            \
    }                                                                         \
    __syncthreads(); /* the ONLY barrier this iteration */                    \
    bf16x8 af[4], bq[2];                                                      \
    _Pragma("unroll") for (int mt = 0; mt < 4; mt++) af[mt] =                 \
        __builtin_bit_cast(bf16x8, *(const ushortx8*)&smem[                   \
            raA + ((s) & 1) * ABUF + mt * 16 * LDSW]);                        \
    _Pragma("unroll") for (int nt = 0; nt < 2; nt++) bq[nt] =                 \
        __builtin_bit_cast(bf16x8, *(const ushortx8*)&smem[                   \
            raB + ((s) & 1) * ABUF + nt * 16 * LDSW]);                        \
    _Pragma("unroll") for (int mt = 0; mt < 4; mt++)                          \
        _Pragma("unroll") for (int nt = 0; nt < 2; nt++) acc[mt][nt] =        \
            __builtin_amdgcn_mfma_f32_16x16x32_bf16(af[mt], bq[nt],           \
                                                    acc[mt][nt], 0, 0, 0);    \
    if ((i) + 1 < KI) {                                                       \
      const int nb = (((s) + 1) & 1) * ABUF;                                  \
      *(ushortx8*)(&smem[wb + nb]) = rA[((s) + 1) & 3];                       \
      *(ushortx8*)(&smem[BOFF + wb + nb]) = rB[((s) + 1) & 3];                \
    }                                                                         \
  }

  for (int io = 0; io < KI; io += 4) {
    GSTEP(io + 0, 0)
    GSTEP(io + 1, 1)
    GSTEP(io + 2, 2)
    GSTEP(io + 3, 3)
  }
#undef GSTEP
}

// GEMM1: Mb = bf16(A@A); deg[row] += rowsum(M) fused (LDS + global atomics).
__global__ __launch_bounds__(512, 2) void gemm1(const u16* __restrict__ Ab,
                                                const u16* __restrict__ Abt,
                                                u16* __restrict__ Mb,
                                                float* __restrict__ deg) {
  __shared__ __align__(16) u16 smem[4 * ABUF];
  floatx4 acc[4][2];
  gemm_core(smem, Ab, Abt, acc);

  // rs aliases A-buf0 (512 B) — free: its last read was iter KI-2, and every
  // wave passed iter KI-1's barrier, so no wave still touches buf0.
  float* rs = (float*)smem;
  const int t = threadIdx.x;
  const int row0 = blockIdx.y * TILE, col0 = blockIdx.x * TILE;
  if (t < TILE) rs[t] = 0.f;
  __syncthreads();
  const int lane = t & 63, w = t >> 6;
  const int wr = (w >> 2) * 64, wc = (w & 3) * 32;
  const int lr = lane & 15, q = lane >> 4;
  float trs[4][4];
#pragma unroll
  for (int mt = 0; mt < 4; mt++)
#pragma unroll
    for (int r = 0; r < 4; r++) trs[mt][r] = 0.f;
#pragma unroll
  for (int mt = 0; mt < 4; mt++)
#pragma unroll
    for (int nt = 0; nt < 2; nt++)
#pragma unroll
      for (int r = 0; r < 4; r++) {
        const float v = acc[mt][nt][r];
        const int rr = row0 + wr + mt * 16 + q * 4 + r;
        const int cc = col0 + wc + nt * 16 + lr;
        Mb[(size_t)rr * N + cc] = f2bf(v);
        trs[mt][r] += v;
      }
#pragma unroll
  for (int mt = 0; mt < 4; mt++)
#pragma unroll
    for (int r = 0; r < 4; r++)
      atomicAdd(&rs[wr + mt * 16 + q * 4 + r], trs[mt][r]);
  __syncthreads();
  if (t < TILE) atomicAdd(&deg[row0 + t], rs[t]);
}

// GEMM2 + fused norm epilogue: out = (8*(M@A) + 2*A) / (4*deg+1) row-scaled.
__global__ __launch_bounds__(512, 2) void gemm2(const u16* __restrict__ Mb,
                                                const u16* __restrict__ Abt,
                                                const float* __restrict__ A,
                                                const float* __restrict__ deg,
                                                float* __restrict__ out) {
  __shared__ __align__(16) u16 smem[4 * ABUF];
  floatx4 acc[4][2];
  gemm_core(smem, Mb, Abt, acc);

  const int t = threadIdx.x;
  const int row0 = blockIdx.y * TILE, col0 = blockIdx.x * TILE;
  const int lane = t & 63, w = t >> 6;
  const int wr = (w >> 2) * 64, wc = (w & 3) * 32;
  const int lr = lane & 15, q = lane >> 4;
#pragma unroll
  for (int mt = 0; mt < 4; mt++)
#pragma unroll
    for (int r = 0; r < 4; r++) {
      const int rr = row0 + wr + mt * 16 + q * 4 + r;
      float d = 4.f * deg[rr] + 1.f;
      if (d <= 1e-10f) d = 1.f;
      const float rd = 1.f / d;
#pragma unroll
      for (int nt = 0; nt < 2; nt++) {
        const int cc = col0 + wc + nt * 16 + lr;
        out[(size_t)rr * N + cc] =
            (8.f * acc[mt][nt][r] + 2.f * A[(size_t)rr * N + cc]) * rd;
      }
    }
}

extern "C" void kernel_launch(void* const* d_in, const int* in_sizes, int n_in,
                              void* d_out, int out_size, void* d_ws, size_t ws_size,
                              hipStream_t stream) {
  const float* A = (const float*)d_in[0];
  // GTConv weights (d_in[1..3]) are irrelevant: softmax over a singleton axis
  // is identically 1, so each conv output is exactly 2*A.
  float* out = (float*)d_out;
  char* ws = (char*)d_ws;
  u16* Ab = (u16*)ws;                        // 8 MB bf16 A row-major
  u16* Abt = (u16*)(ws + NN * 2);            // 8 MB bf16 A transposed
  u16* Mb = (u16*)(ws + NN * 4);             // 8 MB bf16 M = A@A
  float* deg = (float*)(ws + NN * 6);        // 8 KB row sums of M

  hipMemsetAsync(deg, 0, N * sizeof(float), stream);
  cast_tr<<<dim3(N / 32, N / 32), 256, 0, stream>>>(A, Ab, Abt);
  gemm1<<<dim3(N / TILE, N / TILE), 512, 0, stream>>>(Ab, Abt, Mb, deg);
  gemm2<<<dim3(N / TILE, N / TILE), 512, 0, stream>>>(Mb, Abt, A, deg, out);
}